// Round 9
// baseline (4867.281 us; speedup 1.0000x reference)
//
#include <hip/hip_runtime.h>

// GRU recurrence, fused persistent kernel (round 9 = round 8 resubmit;
// round 8 died to an infra failure, no measurement taken).
// WORKING THEORY (from r6's exact 904 GB/s = 1/8 BW plateau + counter x8
// reconciliation): we run on a 1-XCD partition (~32 CUs). r3-r7's 144KB LDS
// meant 1 block/CU -> 64 blocks = 2 SEQUENTIAL rounds. Fix: LDS 16KB +
// launch_bounds(512,4) (VGPR<=128) -> 2 blocks/CU, all 64 blocks resident,
// 4 waves/SIMD. All weights streamed from L2 with pinned batches (r6 proved
// pins sustain full BW), issue-ahead interleave. Math identical to r7.

typedef __attribute__((ext_vector_type(8))) short short8;   // 8 x bf16 MFMA frag
typedef __attribute__((ext_vector_type(4))) float f32x4;

constexpr int B_ = 1024, T_ = 128, I_ = 128, H_ = 256, OUT_ = 64;
constexpr int ROWS = 16;        // batch rows per block
constexpr int NBLK = B_ / ROWS; // 64 blocks

#define DEVI __device__ __forceinline__

DEVI unsigned short f2b(float f) {
    unsigned u = __builtin_bit_cast(unsigned, f);
    u += 0x7fffu + ((u >> 16) & 1u);
    return (unsigned short)(u >> 16);
}
DEVI float sigmoidf_(float x) { float e = __expf(-x); return __fdividef(1.f, 1.f + e); }
DEVI float tanhf_(float x) { float e = __expf(2.f * x); return __fdividef(e - 1.f, e + 1.f); }

DEVI f32x4 ld4(const void* p) { return *reinterpret_cast<const f32x4*>(p); }
DEVI short8 ldg8(const unsigned short* p) {
    return __builtin_bit_cast(short8, *reinterpret_cast<const uint4*>(p));
}
DEVI short8 pack8(f32x4 lo, f32x4 hi) {
    union { unsigned short s[8]; short8 v; } r;
#pragma unroll
    for (int e = 0; e < 4; ++e) { r.s[e] = f2b(lo[e]); r.s[4 + e] = f2b(hi[e]); }
    return r.v;
}
DEVI f32x4 mfma(short8 a, short8 b, f32x4 c) {
    return __builtin_amdgcn_mfma_f32_16x16x32_bf16(a, b, c, 0, 0, 0);
}

// XOR-swizzled [*][256] bf16 tile: byte ^= (row&7)<<4
DEVI unsigned short* swz(unsigned short* base, int row, int col) {
    int byte = (row * H_ + col) * 2;
    byte ^= (row & 7) << 4;
    return (unsigned short*)((char*)base + byte);
}
DEVI const unsigned short* swzc(const unsigned short* base, int row, int col) {
    int byte = (row * H_ + col) * 2;
    byte ^= (row & 7) << 4;
    return (const unsigned short*)((const char*)base + byte);
}

#define PIN8(A) asm volatile("" : "+v"(A[0]),"+v"(A[1]),"+v"(A[2]),"+v"(A[3]),\
    "+v"(A[4]),"+v"(A[5]),"+v"(A[6]),"+v"(A[7]))
#define PIN4(A) asm volatile("" : "+v"(A[0]),"+v"(A[1]),"+v"(A[2]),"+v"(A[3]))

// ---- weight pre-conversion: f32 -> bf16 into d_ws ----
__global__ void cvt_w(const float* __restrict__ src, unsigned short* __restrict__ dst, int n) {
    int i = (blockIdx.x * blockDim.x + threadIdx.x) * 8;
    if (i >= n) return;
    f32x4 lo = ld4(src + i), hi = ld4(src + i + 4);
    union { unsigned short s[8]; uint4 v; } r;
#pragma unroll
    for (int e = 0; e < 4; ++e) { r.s[e] = f2b(lo[e]); r.s[4 + e] = f2b(hi[e]); }
    *reinterpret_cast<uint4*>(dst + i) = r.v;
}

__global__ __launch_bounds__(512, 4) void gru_fused(
    const float* __restrict__ s0,             // [B][H] f32
    const float* __restrict__ a,              // [B][T][I] f32
    const unsigned short* __restrict__ w_ih,  // [3H][I] bf16 (ws)
    const unsigned short* __restrict__ w_hh,  // [3H][H] bf16 (ws)
    const unsigned short* __restrict__ w_rw,  // [OUT][H] bf16 (ws)
    const unsigned short* __restrict__ w_st,  // [H][H] bf16 (ws)
    float* __restrict__ out_r,                // [T][OUT] f32
    float* __restrict__ out_s)                // [B][T][H] f32
{
    __shared__ unsigned short h16[ROWS * H_];   // 8192 B, swizzled
    __shared__ unsigned short hn16[ROWS * H_];  // 8192 B, swizzled

    const int tid = threadIdx.x;
    const int w = tid >> 6;       // wave 0..7
    const int l = tid & 63;
    const int m = l & 15;
    const int kg = l >> 4;
    const int R0 = blockIdx.x * ROWS;
    const int g0 = (2 * w + 0) * 16 + m;   // this wave's two column tiles
    const int g1 = (2 * w + 1) * 16 + m;

    // init h16 (16 rows x 256 cols bf16, swizzled)
    {
        const int pr = tid >> 5, pc = (tid & 31) * 8;
        const float* sp = &s0[(size_t)(R0 + pr) * H_ + pc];
        *reinterpret_cast<uint4*>(swz(h16, pr, pc)) =
            __builtin_bit_cast(uint4, pack8(ld4(sp), ld4(sp + 4)));
    }
    // f32 carry in regs + out_s streaming pointers (advance by H_ per t)
    float hreg0[4], hreg1[4];
    float *o0[4], *o1[4];
#pragma unroll
    for (int v = 0; v < 4; ++v) {
        const int row = kg * 4 + v;
        hreg0[v] = s0[(size_t)(R0 + row) * H_ + g0];
        hreg1[v] = s0[(size_t)(R0 + row) * H_ + g1];
        o0[v] = out_s + (size_t)(R0 + row) * T_ * H_ + g0;
        o1[v] = out_s + (size_t)(R0 + row) * T_ * H_ + g1;
    }
    __syncthreads();

    // x fragments for t=0
    short8 xa[4];
    {
        const float* xr = a + (size_t)(R0 + m) * T_ * I_ + kg * 8;
#pragma unroll
        for (int kt = 0; kt < 4; ++kt)
            xa[kt] = pack8(ld4(xr + kt * 32), ld4(xr + kt * 32 + 4));
    }

    const unsigned short* pwi0 = w_ih + (size_t)g0 * I_ + kg * 8;
    const unsigned short* pwi1 = w_ih + (size_t)g1 * I_ + kg * 8;
    const unsigned short* pwh0 = w_hh + (size_t)g0 * H_ + kg * 8;
    const unsigned short* pwh1 = w_hh + (size_t)g1 * H_ + kg * 8;
    const unsigned short* pst0 = w_st + (size_t)g0 * H_ + kg * 8;
    const unsigned short* pst1 = w_st + (size_t)g1 * H_ + kg * 8;

    for (int t = 0; t < T_; ++t) {
        PIN4(xa);
        // ---------------- phase 1: gate GEMMs, issue-ahead batches -------
        short8 ha[8];
#pragma unroll
        for (int kt = 0; kt < 8; ++kt)
            ha[kt] = ldg8(swzc(h16, m, kt * 32 + kg * 8));

        f32x4 ar0 = {0,0,0,0}, az0 = {0,0,0,0}, ani0 = {0,0,0,0};
        f32x4 ar1 = {0,0,0,0}, az1 = {0,0,0,0}, ani1 = {0,0,0,0};
        f32x4 anh0 = {0,0,0,0}, anh1 = {0,0,0,0};

        short8 bA[8], bB[8];
        // w_ih r (both cols)
#pragma unroll
        for (int kt = 0; kt < 4; ++kt) { bA[kt] = ldg8(pwi0 + kt * 32);
                                         bA[4+kt] = ldg8(pwi1 + kt * 32); }
        // issue w_ih z while r in flight
#pragma unroll
        for (int kt = 0; kt < 4; ++kt) { bB[kt] = ldg8(pwi0 + 256*I_ + kt * 32);
                                         bB[4+kt] = ldg8(pwi1 + 256*I_ + kt * 32); }
        PIN8(bA);
#pragma unroll
        for (int kt = 0; kt < 4; ++kt) { ar0 = mfma(xa[kt], bA[kt], ar0);
                                         ar1 = mfma(xa[kt], bA[4+kt], ar1); }
        // issue w_ih n
#pragma unroll
        for (int kt = 0; kt < 4; ++kt) { bA[kt] = ldg8(pwi0 + 512*I_ + kt * 32);
                                         bA[4+kt] = ldg8(pwi1 + 512*I_ + kt * 32); }
        PIN8(bB);
#pragma unroll
        for (int kt = 0; kt < 4; ++kt) { az0 = mfma(xa[kt], bB[kt], az0);
                                         az1 = mfma(xa[kt], bB[4+kt], az1); }
        // issue w_hh r col0
#pragma unroll
        for (int kt = 0; kt < 8; ++kt) bB[kt] = ldg8(pwh0 + kt * 32);
        PIN8(bA);
#pragma unroll
        for (int kt = 0; kt < 4; ++kt) { ani0 = mfma(xa[kt], bA[kt], ani0);
                                         ani1 = mfma(xa[kt], bA[4+kt], ani1); }
        // issue w_hh r col1
#pragma unroll
        for (int kt = 0; kt < 8; ++kt) bA[kt] = ldg8(pwh1 + kt * 32);
        PIN8(bB);
#pragma unroll
        for (int kt = 0; kt < 8; ++kt) ar0 = mfma(ha[kt], bB[kt], ar0);
        // issue w_hh z col0
#pragma unroll
        for (int kt = 0; kt < 8; ++kt) bB[kt] = ldg8(pwh0 + 256*H_ + kt * 32);
        PIN8(bA);
#pragma unroll
        for (int kt = 0; kt < 8; ++kt) ar1 = mfma(ha[kt], bA[kt], ar1);
        // issue w_hh z col1
#pragma unroll
        for (int kt = 0; kt < 8; ++kt) bA[kt] = ldg8(pwh1 + 256*H_ + kt * 32);
        PIN8(bB);
#pragma unroll
        for (int kt = 0; kt < 8; ++kt) az0 = mfma(ha[kt], bB[kt], az0);
        // issue w_hh n col0
#pragma unroll
        for (int kt = 0; kt < 8; ++kt) bB[kt] = ldg8(pwh0 + 512*H_ + kt * 32);
        PIN8(bA);
#pragma unroll
        for (int kt = 0; kt < 8; ++kt) az1 = mfma(ha[kt], bA[kt], az1);
        // issue w_hh n col1
#pragma unroll
        for (int kt = 0; kt < 8; ++kt) bA[kt] = ldg8(pwh1 + 512*H_ + kt * 32);
        PIN8(bB);
#pragma unroll
        for (int kt = 0; kt < 8; ++kt) anh0 = mfma(ha[kt], bB[kt], anh0);
        PIN8(bA);
#pragma unroll
        for (int kt = 0; kt < 8; ++kt) anh1 = mfma(ha[kt], bA[kt], anh1);

        // ---------------- gates -> h_new (bf16 into hn16) ----------------
#pragma unroll
        for (int v = 0; v < 4; ++v) {
            const int row = kg * 4 + v;
            {
                const float rg = sigmoidf_(ar0[v]);
                const float zg = sigmoidf_(az0[v]);
                const float ng = tanhf_(ani0[v] + rg * anh0[v]);
                *swz(hn16, row, g0) = f2b((1.f - zg) * ng + zg * hreg0[v]);
            }
            {
                const float rg = sigmoidf_(ar1[v]);
                const float zg = sigmoidf_(az1[v]);
                const float ng = tanhf_(ani1[v] + rg * anh1[v]);
                *swz(hn16, row, g1) = f2b((1.f - zg) * ng + zg * hreg1[v]);
            }
        }
        __syncthreads();

        // ---------------- phase 2: s_next = sig(h_new @ w_state^T) -------
        // issue x(t+1) raw loads first: latency hides under the state GEMM
        f32x4 xraw[8];
        {
            const int tn = (t + 1 < T_) ? t + 1 : t;
            const float* xr = a + ((size_t)(R0 + m) * T_ + tn) * I_ + kg * 8;
#pragma unroll
            for (int kt = 0; kt < 4; ++kt) {
                xraw[2 * kt]     = ld4(xr + kt * 32);
                xraw[2 * kt + 1] = ld4(xr + kt * 32 + 4);
            }
        }
        short8 sb0[8], sb1[8];
#pragma unroll
        for (int kt = 0; kt < 8; ++kt) sb0[kt] = ldg8(pst0 + kt * 32);
#pragma unroll
        for (int kt = 0; kt < 8; ++kt) sb1[kt] = ldg8(pst1 + kt * 32);
        short8 na[8];
#pragma unroll
        for (int kt = 0; kt < 8; ++kt)
            na[kt] = ldg8(swzc(hn16, m, kt * 32 + kg * 8));
        f32x4 sa0 = {0,0,0,0}, sa1 = {0,0,0,0};
        PIN8(sb0);
#pragma unroll
        for (int kt = 0; kt < 8; ++kt) sa0 = mfma(na[kt], sb0[kt], sa0);
        PIN8(sb1);
#pragma unroll
        for (int kt = 0; kt < 8; ++kt) sa1 = mfma(na[kt], sb1[kt], sa1);
#pragma unroll
        for (int v = 0; v < 4; ++v) {
            const int row = kg * 4 + v;
            const float u0 = sigmoidf_(sa0[v]);
            const float u1 = sigmoidf_(sa1[v]);
            hreg0[v] = u0; hreg1[v] = u1;
            *swz(h16, row, g0) = f2b(u0);
            *swz(h16, row, g1) = f2b(u1);
            *o0[v] = u0; o0[v] += H_;
            *o1[v] = u1; o1[v] += H_;
        }
        if (blockIdx.x == 0 && w < 4) {   // r_t = sig(h_new[0] @ w_reward^T)
            const int o = w * 16 + m;
            f32x4 accr = {0,0,0,0};
            const unsigned short* p = w_rw + (size_t)o * H_ + kg * 8;
#pragma unroll
            for (int kt = 0; kt < 8; ++kt)
                accr = mfma(na[kt], ldg8(p + kt * 32), accr);
            if (kg == 0)
                out_r[t * OUT_ + o] = sigmoidf_(accr[0]);
        }
        // pack next step's x fragments from the prefetched raw values
        PIN8(xraw);
#pragma unroll
        for (int kt = 0; kt < 4; ++kt)
            xa[kt] = pack8(xraw[2 * kt], xraw[2 * kt + 1]);
        __syncthreads();
    }
}

extern "C" void kernel_launch(void* const* d_in, const int* in_sizes, int n_in,
                              void* d_out, int out_size, void* d_ws, size_t ws_size,
                              hipStream_t stream) {
    const float* s0  = (const float*)d_in[0];
    const float* a   = (const float*)d_in[1];
    const float* wih = (const float*)d_in[2];
    const float* whh = (const float*)d_in[3];
    const float* wrw = (const float*)d_in[4];
    const float* wst = (const float*)d_in[5];

    unsigned short* ws16 = (unsigned short*)d_ws;
    unsigned short* wih16 = ws16;                 // 768*128  = 98304
    unsigned short* whh16 = wih16 + 98304;        // 768*256  = 196608
    unsigned short* wrw16 = whh16 + 196608;       // 64*256   = 16384
    unsigned short* wst16 = wrw16 + 16384;        // 256*256  = 65536

    cvt_w<<<98304  / (256 * 8), 256, 0, stream>>>(wih, wih16, 98304);
    cvt_w<<<196608 / (256 * 8), 256, 0, stream>>>(whh, whh16, 196608);
    cvt_w<<<16384  / (256 * 8), 256, 0, stream>>>(wrw, wrw16, 16384);
    cvt_w<<<65536  / (256 * 8), 256, 0, stream>>>(wst, wst16, 65536);

    float* out = (float*)d_out;
    gru_fused<<<NBLK, 512, 0, stream>>>(s0, a, wih16, whh16, wrw16, wst16,
                                        out, out + (size_t)T_ * OUT_);
}

// Round 10
// 2787.547 us; speedup vs baseline: 1.7461x; 1.7461x over previous
//
#include <hip/hip_runtime.h>

// GRU recurrence (round 10).
// r9 lesson: launch_bounds(512,4) -> VGPR 64 + scratch spills (WRITE 880MB).
// r6 lesson: full chip, blocks co-resident; per-CU weight streaming is the cost.
// This round: (1) gi = x@w_ih^T precomputed into d_ws (recurrence-free GEMM)
//   -> x and w_ih leave the T-loop entirely; (2) w_hh r,z slices pinned into
//   AGPRs ("a" constraint; unified file, beyond the 128-VGPR ceiling);
//   (3) w_state LDS-resident; streamed per step: w_hh n-slice (16 frags) +
//   gi (6x8B) only. ws_size-gated fallback (PREGI=false) computes x inline.

typedef __attribute__((ext_vector_type(8))) short short8;   // 8 x bf16 MFMA frag
typedef __attribute__((ext_vector_type(4))) float f32x4;

constexpr int B_ = 1024, T_ = 128, I_ = 128, H_ = 256, OUT_ = 64;
constexpr int ROWS = 16;
constexpr int NBLK = B_ / ROWS;  // 64

#define DEVI __device__ __forceinline__

DEVI unsigned short f2b(float f) {
    unsigned u = __builtin_bit_cast(unsigned, f);
    u += 0x7fffu + ((u >> 16) & 1u);
    return (unsigned short)(u >> 16);
}
DEVI float b2f(unsigned short s) {
    unsigned u = ((unsigned)s) << 16;
    return __builtin_bit_cast(float, u);
}
DEVI float sigmoidf_(float x) { float e = __expf(-x); return __fdividef(1.f, 1.f + e); }
DEVI float tanhf_(float x) { float e = __expf(2.f * x); return __fdividef(e - 1.f, e + 1.f); }

DEVI f32x4 ld4(const void* p) { return *reinterpret_cast<const f32x4*>(p); }
DEVI short8 ldg8(const unsigned short* p) {
    return __builtin_bit_cast(short8, *reinterpret_cast<const uint4*>(p));
}
DEVI short8 pack8(f32x4 lo, f32x4 hi) {
    union { unsigned short s[8]; short8 v; } r;
#pragma unroll
    for (int e = 0; e < 4; ++e) { r.s[e] = f2b(lo[e]); r.s[4 + e] = f2b(hi[e]); }
    return r.v;
}
DEVI f32x4 mfma(short8 a, short8 b, f32x4 c) {
    return __builtin_amdgcn_mfma_f32_16x16x32_bf16(a, b, c, 0, 0, 0);
}
// 4 consecutive bf16 -> f32x4
DEVI f32x4 ldgit4(const unsigned short* p) {
    unsigned long long raw = *reinterpret_cast<const unsigned long long*>(p);
    f32x4 r;
#pragma unroll
    for (int e = 0; e < 4; ++e) r[e] = b2f((unsigned short)(raw >> (16 * e)));
    return r;
}

// XOR-swizzled [*][256] bf16 tile: byte ^= (row&7)<<4
DEVI unsigned short* swz(unsigned short* base, int row, int col) {
    int byte = (row * H_ + col) * 2;
    byte ^= (row & 7) << 4;
    return (unsigned short*)((char*)base + byte);
}
DEVI const unsigned short* swzc(const unsigned short* base, int row, int col) {
    int byte = (row * H_ + col) * 2;
    byte ^= (row & 7) << 4;
    return (const unsigned short*)((const char*)base + byte);
}

#define PIN8V(A) asm volatile("" : "+v"(A[0]),"+v"(A[1]),"+v"(A[2]),"+v"(A[3]),\
    "+v"(A[4]),"+v"(A[5]),"+v"(A[6]),"+v"(A[7]))
#define PIN8A(A) asm volatile("" : "+a"(A[0]),"+a"(A[1]),"+a"(A[2]),"+a"(A[3]),\
    "+a"(A[4]),"+a"(A[5]),"+a"(A[6]),"+a"(A[7]))

// ---- weight pre-conversion: f32 -> bf16 ----
__global__ void cvt_w(const float* __restrict__ src, unsigned short* __restrict__ dst, int n) {
    int i = (blockIdx.x * blockDim.x + threadIdx.x) * 8;
    if (i >= n) return;
    f32x4 lo = ld4(src + i), hi = ld4(src + i + 4);
    union { unsigned short s[8]; uint4 v; } r;
#pragma unroll
    for (int e = 0; e < 4; ++e) { r.s[e] = f2b(lo[e]); r.s[4 + e] = f2b(hi[e]); }
    *reinterpret_cast<uint4*>(dst + i) = r.v;
}

// ---- gi precompute: git[t][gr][b] = sum_k x[b,t,k] * w_ih[gr,k]  (bf16) ----
// grid: (48 gr-tiles, 128 t), 256 threads (4 waves; wave ww covers b in [ww*256,..))
__global__ __launch_bounds__(256) void gi_gemm(
    const float* __restrict__ a, const unsigned short* __restrict__ wih,
    unsigned short* __restrict__ git)
{
    const int tid = threadIdx.x;
    const int ww = tid >> 6;
    const int l = tid & 63;
    const int m = l & 15, kg = l >> 4;
    const int gr0 = blockIdx.x * 16;
    const int t = blockIdx.y;

    short8 aw[4];
#pragma unroll
    for (int kt = 0; kt < 4; ++kt)
        aw[kt] = ldg8(wih + (size_t)(gr0 + m) * I_ + kt * 32 + kg * 8);

#pragma unroll 4
    for (int bt = 0; bt < 16; ++bt) {
        const int b0 = ww * 256 + bt * 16;
        const float* xr = a + (size_t)(b0 + m) * T_ * I_ + (size_t)t * I_ + kg * 8;
        short8 xb[4];
#pragma unroll
        for (int kt = 0; kt < 4; ++kt)
            xb[kt] = pack8(ld4(xr + kt * 32), ld4(xr + kt * 32 + 4));
        f32x4 acc = {0.f, 0.f, 0.f, 0.f};
#pragma unroll
        for (int kt = 0; kt < 4; ++kt) acc = mfma(aw[kt], xb[kt], acc);
        // D: row (=gr offset) = kg*4+v, col (=b) = m
#pragma unroll
        for (int v = 0; v < 4; ++v)
            git[((size_t)t * 768 + gr0 + kg * 4 + v) * B_ + b0 + m] = f2b(acc[v]);
    }
}

template <bool PREGI>
__global__ __launch_bounds__(512, 2) void gru_fused(
    const float* __restrict__ s0,             // [B][H] f32
    const float* __restrict__ a,              // [B][T][I] f32 (fallback only)
    const unsigned short* __restrict__ git,   // [T][768][B] bf16 (PREGI)
    const unsigned short* __restrict__ w_ih,  // [3H][I] bf16 (fallback only)
    const unsigned short* __restrict__ w_hh,  // [3H][H] bf16
    const unsigned short* __restrict__ w_rw,  // [OUT][H] bf16
    const unsigned short* __restrict__ w_st,  // [H][H] bf16
    float* __restrict__ out_r,                // [T][OUT] f32
    float* __restrict__ out_s)                // [B][T][H] f32
{
    __shared__ unsigned short wst_l[H_ * H_];   // 131072 B, swizzled
    __shared__ unsigned short h16[ROWS * H_];   // 8192 B
    __shared__ unsigned short hn16[ROWS * H_];  // 8192 B

    const int tid = threadIdx.x;
    const int w = tid >> 6;
    const int l = tid & 63;
    const int m = l & 15;
    const int kg = l >> 4;
    const int R0 = blockIdx.x * ROWS;
    const int g0 = (2 * w + 0) * 16 + m;
    const int g1 = (2 * w + 1) * 16 + m;

    // stage w_state into LDS, swizzled
#pragma unroll
    for (int i = 0; i < 16; ++i) {
        const int idx = (tid + i * 512) * 8;
        *reinterpret_cast<uint4*>(swz(wst_l, idx >> 8, idx & 255)) =
            *reinterpret_cast<const uint4*>(w_st + idx);
    }
    // init h16
    {
        const int pr = tid >> 5, pc = (tid & 31) * 8;
        const float* sp = &s0[(size_t)(R0 + pr) * H_ + pc];
        *reinterpret_cast<uint4*>(swz(h16, pr, pc)) =
            __builtin_bit_cast(uint4, pack8(ld4(sp), ld4(sp + 4)));
    }
    float hreg0[4], hreg1[4];
#pragma unroll
    for (int v = 0; v < 4; ++v) {
        hreg0[v] = s0[(size_t)(R0 + kg * 4 + v) * H_ + g0];
        hreg1[v] = s0[(size_t)(R0 + kg * 4 + v) * H_ + g1];
    }

    // AGPR-RESIDENT: w_hh r,z slices for this wave's two column tiles.
    short8 whhR[16], whhZ[16];   // [u*8+kt] -> 128 AGPRs/lane
#pragma unroll
    for (int u = 0; u < 2; ++u) {
        const int g = (u == 0) ? g0 : g1;
#pragma unroll
        for (int kt = 0; kt < 8; ++kt) {
            whhR[u * 8 + kt] = ldg8(w_hh + (size_t)(g)       * H_ + kt * 32 + kg * 8);
            whhZ[u * 8 + kt] = ldg8(w_hh + (size_t)(g + 256) * H_ + kt * 32 + kg * 8);
        }
    }
    PIN8A(whhR); PIN8A((whhR + 8)); PIN8A(whhZ); PIN8A((whhZ + 8));
    __syncthreads();

    const unsigned short* pwn0 = w_hh + (size_t)(512 + g0) * H_ + kg * 8;
    const unsigned short* pwn1 = w_hh + (size_t)(512 + g1) * H_ + kg * 8;

    for (int t = 0; t < T_; ++t) {
        // hold residents live across the loop (loop-carried "+a" chain)
        PIN8A(whhR); PIN8A((whhR + 8)); PIN8A(whhZ); PIN8A((whhZ + 8));

        // ---- issue ALL of this step's global loads up front ----
        short8 wn0[8], wn1[8];
#pragma unroll
        for (int kt = 0; kt < 8; ++kt) wn0[kt] = ldg8(pwn0 + kt * 32);
#pragma unroll
        for (int kt = 0; kt < 8; ++kt) wn1[kt] = ldg8(pwn1 + kt * 32);

        f32x4 ar0, az0, ani0, ar1, az1, ani1;
        if constexpr (PREGI) {
            const unsigned short* gt = git + (size_t)t * 768 * B_ + R0 + kg * 4;
            ar0  = ldgit4(gt + (size_t)(g0)       * B_);
            az0  = ldgit4(gt + (size_t)(g0 + 256) * B_);
            ani0 = ldgit4(gt + (size_t)(g0 + 512) * B_);
            ar1  = ldgit4(gt + (size_t)(g1)       * B_);
            az1  = ldgit4(gt + (size_t)(g1 + 256) * B_);
            ani1 = ldgit4(gt + (size_t)(g1 + 512) * B_);
        } else {
            ar0 = az0 = ani0 = ar1 = az1 = ani1 = f32x4{0.f, 0.f, 0.f, 0.f};
        }

        short8 ha[8];
#pragma unroll
        for (int kt = 0; kt < 8; ++kt)
            ha[kt] = ldg8(swzc(h16, m, kt * 32 + kg * 8));

        if constexpr (!PREGI) {  // fallback: x-part inline
            short8 xa[4];
            const float* xr = a + ((size_t)(R0 + m) * T_ + t) * I_ + kg * 8;
#pragma unroll
            for (int kt = 0; kt < 4; ++kt)
                xa[kt] = pack8(ld4(xr + kt * 32), ld4(xr + kt * 32 + 4));
            const unsigned short* p0 = w_ih + (size_t)g0 * I_ + kg * 8;
            const unsigned short* p1 = w_ih + (size_t)g1 * I_ + kg * 8;
#pragma unroll
            for (int kt = 0; kt < 4; ++kt) {
                ar0  = mfma(xa[kt], ldg8(p0 + kt * 32),            ar0);
                az0  = mfma(xa[kt], ldg8(p0 + 256 * I_ + kt * 32), az0);
                ani0 = mfma(xa[kt], ldg8(p0 + 512 * I_ + kt * 32), ani0);
                ar1  = mfma(xa[kt], ldg8(p1 + kt * 32),            ar1);
                az1  = mfma(xa[kt], ldg8(p1 + 256 * I_ + kt * 32), az1);
                ani1 = mfma(xa[kt], ldg8(p1 + 512 * I_ + kt * 32), ani1);
            }
        }

        // ---- h-part: resident r,z (AGPR) + streamed n ----
        PIN8V(wn0); PIN8V(wn1);
        f32x4 anh0 = {0,0,0,0}, anh1 = {0,0,0,0};
#pragma unroll
        for (int kt = 0; kt < 8; ++kt) {
            ar0  = mfma(ha[kt], whhR[kt],     ar0);
            az0  = mfma(ha[kt], whhZ[kt],     az0);
            anh0 = mfma(ha[kt], wn0[kt],      anh0);
            ar1  = mfma(ha[kt], whhR[8 + kt], ar1);
            az1  = mfma(ha[kt], whhZ[8 + kt], az1);
            anh1 = mfma(ha[kt], wn1[kt],      anh1);
        }
        // ---- gates -> h_new ----
#pragma unroll
        for (int v = 0; v < 4; ++v) {
            const int row = kg * 4 + v;
            {
                const float rg = sigmoidf_(ar0[v]);
                const float zg = sigmoidf_(az0[v]);
                const float ng = tanhf_(ani0[v] + rg * anh0[v]);
                *swz(hn16, row, g0) = f2b((1.f - zg) * ng + zg * hreg0[v]);
            }
            {
                const float rg = sigmoidf_(ar1[v]);
                const float zg = sigmoidf_(az1[v]);
                const float ng = tanhf_(ani1[v] + rg * anh1[v]);
                *swz(hn16, row, g1) = f2b((1.f - zg) * ng + zg * hreg1[v]);
            }
        }
        __syncthreads();

        // ---- phase 2: all operands LDS-resident ----
        short8 na[8];
#pragma unroll
        for (int kt = 0; kt < 8; ++kt)
            na[kt] = ldg8(swzc(hn16, m, kt * 32 + kg * 8));
        f32x4 sa0 = {0,0,0,0}, sa1 = {0,0,0,0};
#pragma unroll
        for (int kt = 0; kt < 8; ++kt) {
            sa0 = mfma(na[kt], ldg8(swzc(wst_l, g0, kt * 32 + kg * 8)), sa0);
            sa1 = mfma(na[kt], ldg8(swzc(wst_l, g1, kt * 32 + kg * 8)), sa1);
        }
#pragma unroll
        for (int v = 0; v < 4; ++v) {
            const int row = kg * 4 + v;
            const float u0 = sigmoidf_(sa0[v]);
            const float u1 = sigmoidf_(sa1[v]);
            hreg0[v] = u0; hreg1[v] = u1;
            *swz(h16, row, g0) = f2b(u0);
            *swz(h16, row, g1) = f2b(u1);
            float* dst = &out_s[((size_t)(R0 + row) * T_ + t) * H_];
            dst[g0] = u0;
            dst[g1] = u1;
        }
        if (blockIdx.x == 0 && w < 4) {  // r_t
            const int o = w * 16 + m;
            f32x4 accr = {0,0,0,0};
            const unsigned short* p = w_rw + (size_t)o * H_ + kg * 8;
#pragma unroll
            for (int kt = 0; kt < 8; ++kt)
                accr = mfma(na[kt], ldg8(p + kt * 32), accr);
            if (kg == 0)
                out_r[t * OUT_ + o] = sigmoidf_(accr[0]);
        }
        __syncthreads();
    }
}

extern "C" void kernel_launch(void* const* d_in, const int* in_sizes, int n_in,
                              void* d_out, int out_size, void* d_ws, size_t ws_size,
                              hipStream_t stream) {
    const float* s0  = (const float*)d_in[0];
    const float* a   = (const float*)d_in[1];
    const float* wih = (const float*)d_in[2];
    const float* whh = (const float*)d_in[3];
    const float* wrw = (const float*)d_in[4];
    const float* wst = (const float*)d_in[5];

    const size_t git_elems = (size_t)T_ * 768 * B_;        // 100,663,296 bf16
    const size_t wtot = 98304 + 196608 + 16384 + 65536;    // 376,832 bf16
    const bool pregi = ws_size >= (git_elems + wtot) * 2;

    unsigned short* ws16 = (unsigned short*)d_ws;
    unsigned short* git  = pregi ? ws16 : nullptr;
    unsigned short* wih16 = ws16 + (pregi ? git_elems : 0);
    unsigned short* whh16 = wih16 + 98304;
    unsigned short* wrw16 = whh16 + 196608;
    unsigned short* wst16 = wrw16 + 16384;

    cvt_w<<<98304  / (256 * 8), 256, 0, stream>>>(wih, wih16, 98304);
    cvt_w<<<196608 / (256 * 8), 256, 0, stream>>>(whh, whh16, 196608);
    cvt_w<<<16384  / (256 * 8), 256, 0, stream>>>(wrw, wrw16, 16384);
    cvt_w<<<65536  / (256 * 8), 256, 0, stream>>>(wst, wst16, 65536);

    float* out = (float*)d_out;
    if (pregi) {
        gi_gemm<<<dim3(48, T_), 256, 0, stream>>>(a, wih16, git);
        gru_fused<true><<<NBLK, 512, 0, stream>>>(s0, a, git, wih16, whh16,
                                                  wrw16, wst16,
                                                  out, out + (size_t)T_ * OUT_);
    } else {
        gru_fused<false><<<NBLK, 512, 0, stream>>>(s0, a, nullptr, wih16, whh16,
                                                   wrw16, wst16,
                                                   out, out + (size_t)T_ * OUT_);
    }
}

// Round 11
// 1446.421 us; speedup vs baseline: 3.3651x; 1.9272x over previous
//
#include <hip/hip_runtime.h>

// GRU recurrence (round 11).
// r10 post-mortem: "+a" pins -> compiler spilled resident weights to scratch
// (WRITE 565MB, VGPR 128). Root cause across r3-r10: launch_bounds cap kept
// arch-VGPR at <=128/256 so ~524KB/step/CU of weights streamed through the
// L2 port + barrier drains (~45K cyc/step, invariant to load count).
// This round: launch_bounds(512,1) lifts the per-wave reg cap (~512 unified);
// w_hh FULLY register-resident (48 frags = 192 regs/lane, "+v" pinned each
// iteration), w_state LDS-resident, gi precomputed -> per-step global traffic
// = 6 git loads + out_s stores only.

typedef __attribute__((ext_vector_type(8))) short short8;   // 8 x bf16 MFMA frag
typedef __attribute__((ext_vector_type(4))) float f32x4;

constexpr int B_ = 1024, T_ = 128, I_ = 128, H_ = 256, OUT_ = 64;
constexpr int ROWS = 16;
constexpr int NBLK = B_ / ROWS;  // 64

#define DEVI __device__ __forceinline__

DEVI unsigned short f2b(float f) {
    unsigned u = __builtin_bit_cast(unsigned, f);
    u += 0x7fffu + ((u >> 16) & 1u);
    return (unsigned short)(u >> 16);
}
DEVI float b2f(unsigned short s) {
    unsigned u = ((unsigned)s) << 16;
    return __builtin_bit_cast(float, u);
}
DEVI float sigmoidf_(float x) { float e = __expf(-x); return __fdividef(1.f, 1.f + e); }
DEVI float tanhf_(float x) { float e = __expf(2.f * x); return __fdividef(e - 1.f, e + 1.f); }

DEVI f32x4 ld4(const void* p) { return *reinterpret_cast<const f32x4*>(p); }
DEVI short8 ldg8(const unsigned short* p) {
    return __builtin_bit_cast(short8, *reinterpret_cast<const uint4*>(p));
}
DEVI short8 pack8(f32x4 lo, f32x4 hi) {
    union { unsigned short s[8]; short8 v; } r;
#pragma unroll
    for (int e = 0; e < 4; ++e) { r.s[e] = f2b(lo[e]); r.s[4 + e] = f2b(hi[e]); }
    return r.v;
}
DEVI f32x4 mfma(short8 a, short8 b, f32x4 c) {
    return __builtin_amdgcn_mfma_f32_16x16x32_bf16(a, b, c, 0, 0, 0);
}
// 4 consecutive bf16 -> f32x4
DEVI f32x4 ldgit4(const unsigned short* p) {
    unsigned long long raw = *reinterpret_cast<const unsigned long long*>(p);
    f32x4 r;
#pragma unroll
    for (int e = 0; e < 4; ++e) r[e] = b2f((unsigned short)(raw >> (16 * e)));
    return r;
}

// XOR-swizzled [*][256] bf16 tile: byte ^= (row&7)<<4
DEVI unsigned short* swz(unsigned short* base, int row, int col) {
    int byte = (row * H_ + col) * 2;
    byte ^= (row & 7) << 4;
    return (unsigned short*)((char*)base + byte);
}
DEVI const unsigned short* swzc(const unsigned short* base, int row, int col) {
    int byte = (row * H_ + col) * 2;
    byte ^= (row & 7) << 4;
    return (const unsigned short*)((const char*)base + byte);
}

#define PIN8V(A) asm volatile("" : "+v"((A)[0]),"+v"((A)[1]),"+v"((A)[2]),\
    "+v"((A)[3]),"+v"((A)[4]),"+v"((A)[5]),"+v"((A)[6]),"+v"((A)[7]))

// ---- weight pre-conversion: f32 -> bf16 ----
__global__ void cvt_w(const float* __restrict__ src, unsigned short* __restrict__ dst, int n) {
    int i = (blockIdx.x * blockDim.x + threadIdx.x) * 8;
    if (i >= n) return;
    f32x4 lo = ld4(src + i), hi = ld4(src + i + 4);
    union { unsigned short s[8]; uint4 v; } r;
#pragma unroll
    for (int e = 0; e < 4; ++e) { r.s[e] = f2b(lo[e]); r.s[4 + e] = f2b(hi[e]); }
    *reinterpret_cast<uint4*>(dst + i) = r.v;
}

// ---- gi precompute: git[t][gr][b] = sum_k x[b,t,k] * w_ih[gr,k]  (bf16) ----
__global__ __launch_bounds__(256) void gi_gemm(
    const float* __restrict__ a, const unsigned short* __restrict__ wih,
    unsigned short* __restrict__ git)
{
    const int tid = threadIdx.x;
    const int ww = tid >> 6;
    const int l = tid & 63;
    const int m = l & 15, kg = l >> 4;
    const int gr0 = blockIdx.x * 16;
    const int t = blockIdx.y;

    short8 aw[4];
#pragma unroll
    for (int kt = 0; kt < 4; ++kt)
        aw[kt] = ldg8(wih + (size_t)(gr0 + m) * I_ + kt * 32 + kg * 8);

#pragma unroll 4
    for (int bt = 0; bt < 16; ++bt) {
        const int b0 = ww * 256 + bt * 16;
        const float* xr = a + (size_t)(b0 + m) * T_ * I_ + (size_t)t * I_ + kg * 8;
        short8 xb[4];
#pragma unroll
        for (int kt = 0; kt < 4; ++kt)
            xb[kt] = pack8(ld4(xr + kt * 32), ld4(xr + kt * 32 + 4));
        f32x4 acc = {0.f, 0.f, 0.f, 0.f};
#pragma unroll
        for (int kt = 0; kt < 4; ++kt) acc = mfma(aw[kt], xb[kt], acc);
#pragma unroll
        for (int v = 0; v < 4; ++v)
            git[((size_t)t * 768 + gr0 + kg * 4 + v) * B_ + b0 + m] = f2b(acc[v]);
    }
}

template <bool PREGI>
__global__ __launch_bounds__(512, 1) void gru_fused(
    const float* __restrict__ s0,             // [B][H] f32
    const float* __restrict__ a,              // [B][T][I] f32 (fallback only)
    const unsigned short* __restrict__ git,   // [T][768][B] bf16 (PREGI)
    const unsigned short* __restrict__ w_ih,  // [3H][I] bf16 (fallback only)
    const unsigned short* __restrict__ w_hh,  // [3H][H] bf16
    const unsigned short* __restrict__ w_rw,  // [OUT][H] bf16
    const unsigned short* __restrict__ w_st,  // [H][H] bf16
    float* __restrict__ out_r,                // [T][OUT] f32
    float* __restrict__ out_s)                // [B][T][H] f32
{
    __shared__ unsigned short wst_l[H_ * H_];   // 131072 B, swizzled
    __shared__ unsigned short h16[ROWS * H_];   // 8192 B
    __shared__ unsigned short hn16[ROWS * H_];  // 8192 B

    const int tid = threadIdx.x;
    const int w = tid >> 6;
    const int l = tid & 63;
    const int m = l & 15;
    const int kg = l >> 4;
    const int R0 = blockIdx.x * ROWS;
    const int g0 = (2 * w + 0) * 16 + m;
    const int g1 = (2 * w + 1) * 16 + m;

    // stage w_state into LDS, swizzled
#pragma unroll
    for (int i = 0; i < 16; ++i) {
        const int idx = (tid + i * 512) * 8;
        *reinterpret_cast<uint4*>(swz(wst_l, idx >> 8, idx & 255)) =
            *reinterpret_cast<const uint4*>(w_st + idx);
    }
    // init h16
    {
        const int pr = tid >> 5, pc = (tid & 31) * 8;
        const float* sp = &s0[(size_t)(R0 + pr) * H_ + pc];
        *reinterpret_cast<uint4*>(swz(h16, pr, pc)) =
            __builtin_bit_cast(uint4, pack8(ld4(sp), ld4(sp + 4)));
    }
    float hreg0[4], hreg1[4];
#pragma unroll
    for (int v = 0; v < 4; ++v) {
        hreg0[v] = s0[(size_t)(R0 + kg * 4 + v) * H_ + g0];
        hreg1[v] = s0[(size_t)(R0 + kg * 4 + v) * H_ + g1];
    }

    // REGISTER-RESIDENT: the whole w_hh slice this wave needs.
    // 48 fragments x 4 VGPR = 192 regs/lane (fits: launch_bounds(512,1)).
    short8 whR[16], whZ[16], whN[16];   // [u*8+kt]
#pragma unroll
    for (int u = 0; u < 2; ++u) {
        const int g = (u == 0) ? g0 : g1;
#pragma unroll
        for (int kt = 0; kt < 8; ++kt) {
            whR[u * 8 + kt] = ldg8(w_hh + (size_t)(g)       * H_ + kt * 32 + kg * 8);
            whZ[u * 8 + kt] = ldg8(w_hh + (size_t)(g + 256) * H_ + kt * 32 + kg * 8);
            whN[u * 8 + kt] = ldg8(w_hh + (size_t)(g + 512) * H_ + kt * 32 + kg * 8);
        }
    }
    __syncthreads();

    for (int t = 0; t < T_; ++t) {
        // hold residents live (loop-carried "+v" chain; no remat possible)
        PIN8V(whR); PIN8V(whR + 8);
        PIN8V(whZ); PIN8V(whZ + 8);
        PIN8V(whN); PIN8V(whN + 8);

        // ---- gi (precomputed x-part): the ONLY global loads this phase ----
        f32x4 ar0, az0, ani0, ar1, az1, ani1;
        if constexpr (PREGI) {
            const unsigned short* gt = git + (size_t)t * 768 * B_ + R0 + kg * 4;
            ar0  = ldgit4(gt + (size_t)(g0)       * B_);
            az0  = ldgit4(gt + (size_t)(g0 + 256) * B_);
            ani0 = ldgit4(gt + (size_t)(g0 + 512) * B_);
            ar1  = ldgit4(gt + (size_t)(g1)       * B_);
            az1  = ldgit4(gt + (size_t)(g1 + 256) * B_);
            ani1 = ldgit4(gt + (size_t)(g1 + 512) * B_);
        } else {
            ar0 = az0 = ani0 = ar1 = az1 = ani1 = f32x4{0.f, 0.f, 0.f, 0.f};
        }

        short8 ha[8];
#pragma unroll
        for (int kt = 0; kt < 8; ++kt)
            ha[kt] = ldg8(swzc(h16, m, kt * 32 + kg * 8));

        if constexpr (!PREGI) {  // fallback: x-part inline (streams w_ih)
            short8 xa[4];
            const float* xr = a + ((size_t)(R0 + m) * T_ + t) * I_ + kg * 8;
#pragma unroll
            for (int kt = 0; kt < 4; ++kt)
                xa[kt] = pack8(ld4(xr + kt * 32), ld4(xr + kt * 32 + 4));
            const unsigned short* p0 = w_ih + (size_t)g0 * I_ + kg * 8;
            const unsigned short* p1 = w_ih + (size_t)g1 * I_ + kg * 8;
#pragma unroll
            for (int kt = 0; kt < 4; ++kt) {
                ar0  = mfma(xa[kt], ldg8(p0 + kt * 32),            ar0);
                az0  = mfma(xa[kt], ldg8(p0 + 256 * I_ + kt * 32), az0);
                ani0 = mfma(xa[kt], ldg8(p0 + 512 * I_ + kt * 32), ani0);
                ar1  = mfma(xa[kt], ldg8(p1 + kt * 32),            ar1);
                az1  = mfma(xa[kt], ldg8(p1 + 256 * I_ + kt * 32), az1);
                ani1 = mfma(xa[kt], ldg8(p1 + 512 * I_ + kt * 32), ani1);
            }
        }

        // ---- h-part: ALL weights in registers ----
        f32x4 anh0 = {0,0,0,0}, anh1 = {0,0,0,0};
#pragma unroll
        for (int kt = 0; kt < 8; ++kt) {
            ar0  = mfma(ha[kt], whR[kt],     ar0);
            az0  = mfma(ha[kt], whZ[kt],     az0);
            anh0 = mfma(ha[kt], whN[kt],     anh0);
            ar1  = mfma(ha[kt], whR[8 + kt], ar1);
            az1  = mfma(ha[kt], whZ[8 + kt], az1);
            anh1 = mfma(ha[kt], whN[8 + kt], anh1);
        }
        // ---- gates -> h_new ----
#pragma unroll
        for (int v = 0; v < 4; ++v) {
            const int row = kg * 4 + v;
            {
                const float rg = sigmoidf_(ar0[v]);
                const float zg = sigmoidf_(az0[v]);
                const float ng = tanhf_(ani0[v] + rg * anh0[v]);
                *swz(hn16, row, g0) = f2b((1.f - zg) * ng + zg * hreg0[v]);
            }
            {
                const float rg = sigmoidf_(ar1[v]);
                const float zg = sigmoidf_(az1[v]);
                const float ng = tanhf_(ani1[v] + rg * anh1[v]);
                *swz(hn16, row, g1) = f2b((1.f - zg) * ng + zg * hreg1[v]);
            }
        }
        __syncthreads();

        // ---- phase 2: all operands LDS/register-resident ----
        short8 na[8];
#pragma unroll
        for (int kt = 0; kt < 8; ++kt)
            na[kt] = ldg8(swzc(hn16, m, kt * 32 + kg * 8));
        f32x4 sa0 = {0,0,0,0}, sa1 = {0,0,0,0};
#pragma unroll
        for (int kt = 0; kt < 8; ++kt) {
            sa0 = mfma(na[kt], ldg8(swzc(wst_l, g0, kt * 32 + kg * 8)), sa0);
            sa1 = mfma(na[kt], ldg8(swzc(wst_l, g1, kt * 32 + kg * 8)), sa1);
        }
#pragma unroll
        for (int v = 0; v < 4; ++v) {
            const int row = kg * 4 + v;
            const float u0 = sigmoidf_(sa0[v]);
            const float u1 = sigmoidf_(sa1[v]);
            hreg0[v] = u0; hreg1[v] = u1;
            *swz(h16, row, g0) = f2b(u0);
            *swz(h16, row, g1) = f2b(u1);
            float* dst = &out_s[((size_t)(R0 + row) * T_ + t) * H_];
            dst[g0] = u0;
            dst[g1] = u1;
        }
        if (blockIdx.x == 0 && w < 4) {  // r_t
            const int o = w * 16 + m;
            f32x4 accr = {0,0,0,0};
            const unsigned short* p = w_rw + (size_t)o * H_ + kg * 8;
#pragma unroll
            for (int kt = 0; kt < 8; ++kt)
                accr = mfma(na[kt], ldg8(p + kt * 32), accr);
            if (kg == 0)
                out_r[t * OUT_ + o] = sigmoidf_(accr[0]);
        }
        __syncthreads();
    }
}

extern "C" void kernel_launch(void* const* d_in, const int* in_sizes, int n_in,
                              void* d_out, int out_size, void* d_ws, size_t ws_size,
                              hipStream_t stream) {
    const float* s0  = (const float*)d_in[0];
    const float* a   = (const float*)d_in[1];
    const float* wih = (const float*)d_in[2];
    const float* whh = (const float*)d_in[3];
    const float* wrw = (const float*)d_in[4];
    const float* wst = (const float*)d_in[5];

    const size_t git_elems = (size_t)T_ * 768 * B_;        // 100,663,296 bf16
    const size_t wtot = 98304 + 196608 + 16384 + 65536;    // 376,832 bf16
    const bool pregi = ws_size >= (git_elems + wtot) * 2;

    unsigned short* ws16 = (unsigned short*)d_ws;
    unsigned short* git  = pregi ? ws16 : nullptr;
    unsigned short* wih16 = ws16 + (pregi ? git_elems : 0);
    unsigned short* whh16 = wih16 + 98304;
    unsigned short* wrw16 = whh16 + 196608;
    unsigned short* wst16 = wrw16 + 16384;

    cvt_w<<<98304  / (256 * 8), 256, 0, stream>>>(wih, wih16, 98304);
    cvt_w<<<196608 / (256 * 8), 256, 0, stream>>>(whh, whh16, 196608);
    cvt_w<<<16384  / (256 * 8), 256, 0, stream>>>(wrw, wrw16, 16384);
    cvt_w<<<65536  / (256 * 8), 256, 0, stream>>>(wst, wst16, 65536);

    float* out = (float*)d_out;
    if (pregi) {
        gi_gemm<<<dim3(48, T_), 256, 0, stream>>>(a, wih16, git);
        gru_fused<true><<<NBLK, 512, 0, stream>>>(s0, a, git, wih16, whh16,
                                                  wrw16, wst16,
                                                  out, out + (size_t)T_ * OUT_);
    } else {
        gru_fused<false><<<NBLK, 512, 0, stream>>>(s0, a, nullptr, wih16, whh16,
                                                   wrw16, wst16,
                                                   out, out + (size_t)T_ * OUT_);
    }
}